// Round 26
// baseline (611.061 us; speedup 1.0000x reference)
//
#include <hip/hip_runtime.h>
#include <stdint.h>

#define BB 8
#define CCH 64
#define NPB 4096
#define NPTS (BB*NPB)   // 32768
#define PPW 8           // points per wave in k_mlp2
#define SCAP 192        // survivor cap per row

typedef float  f32x2  __attribute__((ext_vector_type(2)));
typedef float  f32x4v __attribute__((ext_vector_type(4)));
typedef short  bf16x8 __attribute__((ext_vector_type(8)));
typedef unsigned short u16x8 __attribute__((ext_vector_type(8)));
typedef unsigned long long u64;
typedef unsigned int u32;

// round-to-nearest-even f32 -> bf16 bits
__device__ __forceinline__ unsigned short f2bf(float x) {
    u32 u = __float_as_uint(x);
    u += 0x7FFFu + ((u >> 16) & 1u);
    return (unsigned short)(u >> 16);
}

// bitonic sort16 ascending (static indices, branchless) — proven since R6
template<typename T>
__device__ __forceinline__ void sort16(T* key) {
#pragma unroll
    for (int kk = 2; kk <= 16; kk <<= 1) {
#pragma unroll
        for (int j = kk >> 1; j > 0; j >>= 1) {
#pragma unroll
            for (int i = 0; i < 16; ++i) {
                int l = i ^ j;
                if (l > i) {
                    bool up = ((i & kk) == 0);
                    T a = key[i], c = key[l];
                    bool cond = up ? (c < a) : (a < c);
                    key[i] = cond ? c : a;
                    key[l] = cond ? a : c;
                }
            }
        }
    }
}

// keep 16 smallest of (list asc, key asc) -> list asc — proven since R6
template<typename T>
__device__ __forceinline__ void merge16(T* list, const T* key) {
    T m[16];
#pragma unroll
    for (int i = 0; i < 16; ++i) {
        T a = list[i], c = key[15 - i];
        m[i] = (c < a) ? c : a;
    }
#pragma unroll
    for (int j = 8; j > 0; j >>= 1) {
#pragma unroll
        for (int i = 0; i < 16; ++i) {
            if ((i & j) == 0) {
                T a = m[i], c = m[i + j];
                bool cond = c < a;
                m[i]     = cond ? c : a;
                m[i + j] = cond ? a : c;
            }
        }
    }
#pragma unroll
    for (int i = 0; i < 16; ++i) list[i] = m[i];
}

// ---------------- K1: fused transpose + sq + bf16 cast (PASSING since R19) ----------------
__global__ void k_transpose(const float* __restrict__ x, float* __restrict__ xb,
                            unsigned short* __restrict__ xh, float* __restrict__ sq) {
    __shared__ float tile[64][65];
    int b  = blockIdx.y;
    int n0 = blockIdx.x * 64;
    int tx = threadIdx.x, ty = threadIdx.y;   // 64 x 8
    const float* xp = x + (size_t)b * CCH * NPB;
#pragma unroll
    for (int r = 0; r < 8; ++r) {
        int c = ty + r * 8;
        tile[c][tx] = xp[(size_t)c * NPB + n0 + tx];
    }
    __syncthreads();
    float* xbp = xb + ((size_t)b * NPB + n0) * CCH;
    unsigned short* xhp = xh + ((size_t)b * NPB + n0) * CCH;
    float* sqp = sq + (size_t)b * NPB + n0;
#pragma unroll
    for (int r = 0; r < 8; ++r) {
        int nn = ty + r * 8;
        float v = tile[tx][nn];
        xbp[(size_t)nn * CCH + tx] = v;
        xhp[(size_t)nn * CCH + tx] = f2bf(v);
        float s = v * v;
#pragma unroll
        for (int o = 32; o > 0; o >>= 1) s += __shfl_xor(s, o);
        if (tx == 0) sqp[nn] = s;
    }
}

// ---------------- K1d: fold + transpose weights to bf16 (PASSING) ----------------
__global__ void k_prepw(const float* __restrict__ W1, const float* __restrict__ W2,
                        unsigned short* __restrict__ W1t, unsigned short* __restrict__ W2t) {
    int t = blockIdx.x * 256 + threadIdx.x;     // 12288 threads
    if (t < 8192) {
        int o = t >> 7, k = t & 127;
        float v = (k < 64) ? (W1[k * 64 + o] - W1[(64 + k) * 64 + o]) : W1[k * 64 + o];
        W1t[o * 128 + k] = f2bf(v);
    } else if (t < 12288) {
        int u = t - 8192;
        int o = u >> 6, j = u & 63;
        W2t[o * 64 + j] = f2bf(W2[j * 64 + o]);
    }
}

// ---------------- K2a: SAMPLED MFMA tile + per-row block top-16 (R25 k_gemm, 16 blocks) ----------------
// Covers 16 of 64 col-blocks (cols bx*256..bx*256+63) -> per-row top-16 of a
// 1024-col sample. Union's 16th-smallest is a GUARANTEED upper bound on the
// true 16th-NN bf16 distance (subset property).
__global__ __launch_bounds__(256) void k_gemm1(const unsigned short* __restrict__ xh,
                                               const float* __restrict__ sq,
                                               u32* __restrict__ cand16) {
    __shared__ float dtile[64][65];
    __shared__ u32 llist[64][65];
    int b = blockIdx.y >> 6;                    // scalar batch
    const unsigned short* xhB = xh + (size_t)b * NPB * CCH;
    const float* sqB = sq + (size_t)b * NPB;
    u32* candB = cand16 + (size_t)b * 16 * NPB * 16;
    int l = threadIdx.x & 63;
    int w = threadIdx.x >> 6;
    int m0 = (blockIdx.y & 63) * 64;
    int n0 = blockIdx.x * 256;                  // every 4th 64-col block
    const unsigned short* ap = xhB + (size_t)(m0 + w * 16 + (l & 15)) * CCH + ((l >> 4) * 8);
    bf16x8 a0 = *(const bf16x8*)ap;
    bf16x8 a1 = *(const bf16x8*)(ap + 32);
    f32x4v z = {0.f, 0.f, 0.f, 0.f};
    f32x4v acc[4];
#pragma unroll
    for (int cg = 0; cg < 4; ++cg) {
        const unsigned short* bp = xhB + (size_t)(n0 + cg * 16 + (l & 15)) * CCH + ((l >> 4) * 8);
        bf16x8 b0 = *(const bf16x8*)bp;
        bf16x8 b1 = *(const bf16x8*)(bp + 32);
        acc[cg] = __builtin_amdgcn_mfma_f32_16x16x32_bf16(a0, b0, z, 0, 0, 0);
        acc[cg] = __builtin_amdgcn_mfma_f32_16x16x32_bf16(a1, b1, acc[cg], 0, 0, 0);
    }
    int rb = m0 + w * 16 + (l >> 4) * 4;
    float4 sr = *(const float4*)(sqB + rb);
    float sqr[4] = {sr.x, sr.y, sr.z, sr.w};
#pragma unroll
    for (int cg = 0; cg < 4; ++cg) {
        int cit = cg * 16 + (l & 15);
        float sc = sqB[n0 + cit];
#pragma unroll
        for (int j = 0; j < 4; ++j) {
            float v = fmaxf(fmaf(-2.f, acc[cg][j], sqr[j] + sc), 0.f);
            dtile[w * 16 + (l >> 4) * 4 + j][cit] = v;
        }
    }
    __syncthreads();
    {
        int row = l, ch = w;
        u32 key[16];
#pragma unroll
        for (int e = 0; e < 16; ++e) {
            float v = dtile[row][ch * 16 + e];
            key[e] = ((u32)f2bf(v) << 16) | (u32)(n0 + ch * 16 + e);
        }
        sort16(key);
#pragma unroll
        for (int i = 0; i < 16; ++i) llist[row][ch * 16 + i] = key[i];
    }
    __syncthreads();
    if (threadIdx.x < 128) {
        int r2 = threadIdx.x & 63;
        int hf = threadIdx.x >> 6;
        u32 a[16], c[16];
#pragma unroll
        for (int i = 0; i < 16; ++i) a[i] = llist[r2][hf * 32 + i];
#pragma unroll
        for (int i = 0; i < 16; ++i) c[i] = llist[r2][hf * 32 + 16 + i];
        merge16(a, c);
#pragma unroll
        for (int i = 0; i < 16; ++i) llist[r2][hf * 32 + i] = a[i];
    }
    __syncthreads();
    if (threadIdx.x < 64) {
        int r2 = threadIdx.x;
        u32 list[16], tmp[16];
#pragma unroll
        for (int i = 0; i < 16; ++i) list[i] = llist[r2][i];
#pragma unroll
        for (int i = 0; i < 16; ++i) tmp[i] = llist[r2][32 + i];
        merge16(list, tmp);
        u32* cp = candB + ((size_t)blockIdx.x * NPB + (m0 + r2)) * 16;
#pragma unroll
        for (int i = 0; i < 16; ++i) cp[i] = list[i];
    }
}

// ---------------- K2b: per-row tau = 16th-smallest sampled bf16 value ----------------
__global__ __launch_bounds__(256, 1) void k_tau(const u32* __restrict__ cand16,
                                                u32* __restrict__ tau) {
    int l  = threadIdx.x & 63;
    int rl = __builtin_amdgcn_readfirstlane(threadIdx.x >> 6);
    int rowg = blockIdx.x * 4 + rl;
    int b    = rowg >> 12;
    int row  = rowg & 4095;
    const u32* candB = cand16 + (size_t)b * 16 * NPB * 16;
    u32 karr[16];
    if (l < 16) {
        const uint4* cp = (const uint4*)(candB + ((size_t)l * NPB + row) * 16);
#pragma unroll
        for (int i = 0; i < 4; ++i) {
            uint4 v = cp[i];
            karr[4*i] = v.x; karr[4*i+1] = v.y; karr[4*i+2] = v.z; karr[4*i+3] = v.w;
        }
    } else {
#pragma unroll
        for (int i = 0; i < 16; ++i) karr[i] = 0xFFFFFFFFu;
    }
    u32 lo = 0, hi = 0x7FFFu;
#pragma unroll
    for (int it = 0; it < 15; ++it) {
        u32 mid = (lo + hi) >> 1;
        int c = 0;
#pragma unroll
        for (int i = 0; i < 16; ++i) c += ((karr[i] >> 16) <= mid) ? 1 : 0;
#pragma unroll
        for (int o = 32; o > 0; o >>= 1) c += __shfl_xor(c, o);
        bool ge = (c >= 16);
        lo = ge ? lo : (mid + 1);
        hi = ge ? mid : hi;
    }
    if (l == 0) tau[rowg] = hi;
}

// ---------------- K2c: full MFMA pass, threshold compare + survivor append ----------------
// MFMA + epilogue math byte-identical to k_gemm1; NO LDS / sort / barriers.
// survivor iff f2bf(d~) <= tau[row] (same bf16 space -> superset of true
// top-16 guaranteed). Append via atomicAdd; order nondeterministic but the
// survivor SET is deterministic and k_sel sorts by exact (d,col).
__global__ __launch_bounds__(256) void k_gemm2(const unsigned short* __restrict__ xh,
                                               const float* __restrict__ sq,
                                               const u32* __restrict__ tau,
                                               int* __restrict__ cnt,
                                               u32* __restrict__ surv) {
    int b = blockIdx.y >> 6;                    // scalar batch
    const unsigned short* xhB = xh + (size_t)b * NPB * CCH;
    const float* sqB = sq + (size_t)b * NPB;
    int l = threadIdx.x & 63;
    int w = threadIdx.x >> 6;
    int m0 = (blockIdx.y & 63) * 64;
    int n0 = blockIdx.x * 64;
    const unsigned short* ap = xhB + (size_t)(m0 + w * 16 + (l & 15)) * CCH + ((l >> 4) * 8);
    bf16x8 a0 = *(const bf16x8*)ap;
    bf16x8 a1 = *(const bf16x8*)(ap + 32);
    f32x4v z = {0.f, 0.f, 0.f, 0.f};
    f32x4v acc[4];
#pragma unroll
    for (int cg = 0; cg < 4; ++cg) {
        const unsigned short* bp = xhB + (size_t)(n0 + cg * 16 + (l & 15)) * CCH + ((l >> 4) * 8);
        bf16x8 b0 = *(const bf16x8*)bp;
        bf16x8 b1 = *(const bf16x8*)(bp + 32);
        acc[cg] = __builtin_amdgcn_mfma_f32_16x16x32_bf16(a0, b0, z, 0, 0, 0);
        acc[cg] = __builtin_amdgcn_mfma_f32_16x16x32_bf16(a1, b1, acc[cg], 0, 0, 0);
    }
    int rb = m0 + w * 16 + (l >> 4) * 4;
    float4 sr = *(const float4*)(sqB + rb);
    float sqr[4] = {sr.x, sr.y, sr.z, sr.w};
    u32 tv[4];
#pragma unroll
    for (int j = 0; j < 4; ++j) tv[j] = tau[(b << 12) + rb + j];
#pragma unroll
    for (int cg = 0; cg < 4; ++cg) {
        int cit = cg * 16 + (l & 15);
        float sc = sqB[n0 + cit];
#pragma unroll
        for (int j = 0; j < 4; ++j) {
            float v = fmaxf(fmaf(-2.f, acc[cg][j], sqr[j] + sc), 0.f);
            u32 bv = (u32)f2bf(v);
            if (bv <= tv[j]) {
                int rg = (b << 12) + rb + j;
                int slot = atomicAdd(&cnt[rg], 1);
                if (slot < SCAP) surv[(size_t)rg * SCAP + slot] = (u32)(n0 + cit);
            }
        }
    }
}

// ---------------- K3: exact fp32 refine of survivors -> top-16 idx ----------------
// wave per row; 3 passes of 64 survivors: exact fp32 d (byte-identical R25
// math), 64-lane bitonic sort (R19-proven), lower-64 bitonic merges.
__global__ __launch_bounds__(256, 1) void k_sel(const u32* __restrict__ surv,
                                                const int* __restrict__ cnt,
                                                const float* __restrict__ xb,
                                                const float* __restrict__ sq,
                                                int* __restrict__ idxo) {
    int l  = threadIdx.x & 63;
    int rl = __builtin_amdgcn_readfirstlane(threadIdx.x >> 6);
    int rowg = blockIdx.x * 4 + rl;             // scalar
    int b    = rowg >> 12;
    int row  = rowg & 4095;
    const float* xbB = xb + ((size_t)b << 12) * CCH;
    const float* sqB = sq + ((size_t)b << 12);
    const float* xr = xbB + (size_t)row * CCH;  // uniform -> s_load
    float rr[64];
#pragma unroll
    for (int i = 0; i < 16; ++i) {
        float4 v = *(const float4*)(xr + i * 4);
        rr[4*i] = v.x; rr[4*i+1] = v.y; rr[4*i+2] = v.z; rr[4*i+3] = v.w;
    }
    int n = cnt[rowg];                          // scalar
    n = n > SCAP ? SCAP : n;
    u64 m = ~0ULL;
#pragma unroll
    for (int p = 0; p < 3; ++p) {
        if (p == 0 || n > p * 64) {
            int s = p * 64 + l;
            u64 key = ~0ULL;
            if (s < n) {
                int col = (int)surv[(size_t)rowg * SCAP + s];
                const float* xj = xbB + (size_t)col * CCH;
                float lod = 0.f, hid = 0.f;
#pragma unroll
                for (int q = 0; q < 8; ++q) {
                    float4 v  = *(const float4*)(xj + q * 4);
                    float4 wv = *(const float4*)(xj + 32 + q * 4);
                    lod = fmaf(v.x,  rr[4*q+0], lod);
                    lod = fmaf(v.y,  rr[4*q+1], lod);
                    lod = fmaf(v.z,  rr[4*q+2], lod);
                    lod = fmaf(v.w,  rr[4*q+3], lod);
                    hid = fmaf(wv.x, rr[32+4*q+0], hid);
                    hid = fmaf(wv.y, rr[32+4*q+1], hid);
                    hid = fmaf(wv.z, rr[32+4*q+2], hid);
                    hid = fmaf(wv.w, rr[32+4*q+3], hid);
                }
                float d = fmaf(-2.f, lod + hid, sqB[col]);
                u32 fb = __float_as_uint(d);
                fb ^= (fb >> 31) ? 0xFFFFFFFFu : 0x80000000u;   // monotonic
                key = ((u64)fb << 32) | (u32)col;
            }
            // 64-lane bitonic sort ascending (R19-proven)
#pragma unroll
            for (int kk = 2; kk <= 64; kk <<= 1) {
#pragma unroll
                for (int j = kk >> 1; j > 0; j >>= 1) {
                    u64 pz = (u64)__shfl_xor((long long)key, j);
                    bool keep_min = (((l & kk) == 0) == ((l & j) == 0));
                    bool plt = pz < key;
                    key = keep_min ? (plt ? pz : key) : (plt ? key : pz);
                }
            }
            if (p == 0) {
                m = key;
            } else {
                // lower 64 of merge(m asc, key asc): elementwise min with
                // reversed partner -> bitonic; then clean.
                u64 q = (u64)__shfl((long long)key, 63 - l);
                u64 mm = q < m ? q : m;
#pragma unroll
                for (int j = 32; j > 0; j >>= 1) {
                    u64 pz = (u64)__shfl_xor((long long)mm, j);
                    bool low = ((l & j) == 0);
                    bool plt = pz < mm;
                    mm = low ? (plt ? pz : mm) : (plt ? mm : pz);
                }
                m = mm;
            }
        }
    }
    if (l < 16) idxo[(size_t)rowg * 16 + l] = (int)(m & 0xFFFFFFFFu);
}

// ---------------- K4: MFMA edge-MLP + max over K (R18-R25 body, PASSING) ----------------
__global__ __launch_bounds__(256, 1) void k_mlp2(const unsigned short* __restrict__ xh,
                                                 const int* __restrict__ idx,
                                                 const unsigned short* __restrict__ W1t,
                                                 const unsigned short* __restrict__ W2t,
                                                 const float* __restrict__ b1,
                                                 const float* __restrict__ b2,
                                                 float* __restrict__ out) {
    __shared__ unsigned short h1l[4][16 * 72];
    int l   = threadIdx.x & 63;
    int wib = threadIdx.x >> 6;
    int e   = l & 15;
    int kg  = l >> 4;
    int wave = blockIdx.x * 4 + wib;            // 0..4095
    unsigned short* hl = h1l[wib];

    bf16x8 w1f[4][4];
#pragma unroll
    for (int nt = 0; nt < 4; ++nt)
#pragma unroll
        for (int s = 0; s < 4; ++s)
            w1f[nt][s] = *(const bf16x8*)(W1t + (size_t)(nt * 16 + e) * 128 + s * 32 + kg * 8);
    bf16x8 w2f[4][2];
#pragma unroll
    for (int nt = 0; nt < 4; ++nt)
#pragma unroll
        for (int s = 0; s < 2; ++s)
            w2f[nt][s] = *(const bf16x8*)(W2t + (size_t)(nt * 16 + e) * 64 + s * 32 + kg * 8);
    float b1v[4], b2v[4];
#pragma unroll
    for (int nt = 0; nt < 4; ++nt) { b1v[nt] = b1[nt * 16 + e]; b2v[nt] = b2[nt * 16 + e]; }

    int p0 = wave * PPW;
    int bb = p0 >> 12;
    int n0 = p0 & 4095;
    const unsigned short* xhB = xh + ((size_t)bb << 12) * CCH;
    f32x4v z = {0.f, 0.f, 0.f, 0.f};
    float mx[4][PPW];
#pragma unroll
    for (int nt = 0; nt < 4; ++nt)
#pragma unroll
        for (int pi = 0; pi < PPW; ++pi) mx[nt][pi] = 0.f;

#pragma unroll
    for (int pi = 0; pi < PPW; ++pi) {
        int n = n0 + pi;
        int je = idx[((size_t)(p0 + pi)) * 16 + e];
        bf16x8 a[4];
        a[0] = *(const bf16x8*)(xhB + (size_t)n * 64 + kg * 8);
        a[1] = *(const bf16x8*)(xhB + (size_t)n * 64 + 32 + kg * 8);
        a[2] = *(const bf16x8*)(xhB + (size_t)je * 64 + kg * 8);
        a[3] = *(const bf16x8*)(xhB + (size_t)je * 64 + 32 + kg * 8);
#pragma unroll
        for (int nt = 0; nt < 4; ++nt) {
            f32x4v acc = z;
#pragma unroll
            for (int s = 0; s < 4; ++s)
                acc = __builtin_amdgcn_mfma_f32_16x16x32_bf16(a[s], w1f[nt][s], acc, 0, 0, 0);
#pragma unroll
            for (int j = 0; j < 4; ++j) {
                float h = fmaxf(acc[j] + b1v[nt], 0.f);
                hl[(kg * 4 + j) * 72 + nt * 16 + e] = f2bf(h);
            }
        }
        bf16x8 a2[2];
        a2[0] = *(const bf16x8*)(hl + (size_t)e * 72 + kg * 8);
        a2[1] = *(const bf16x8*)(hl + (size_t)e * 72 + 32 + kg * 8);
#pragma unroll
        for (int nt = 0; nt < 4; ++nt) {
            f32x4v acc = z;
            acc = __builtin_amdgcn_mfma_f32_16x16x32_bf16(a2[0], w2f[nt][0], acc, 0, 0, 0);
            acc = __builtin_amdgcn_mfma_f32_16x16x32_bf16(a2[1], w2f[nt][1], acc, 0, 0, 0);
            float m4 = 0.f;
#pragma unroll
            for (int j = 0; j < 4; ++j)
                m4 = fmaxf(m4, fmaxf(acc[j] + b2v[nt], 0.f));
            mx[nt][pi] = m4;
        }
    }
#pragma unroll
    for (int nt = 0; nt < 4; ++nt)
#pragma unroll
        for (int pi = 0; pi < PPW; ++pi) {
            float v = mx[nt][pi];
            v = fmaxf(v, __shfl_xor(v, 16));
            v = fmaxf(v, __shfl_xor(v, 32));
            mx[nt][pi] = v;
        }
    if (kg == 0) {
#pragma unroll
        for (int nt = 0; nt < 4; ++nt) {
            float* op = out + ((size_t)bb * 64 + nt * 16 + e) * NPB + n0;
#pragma unroll
            for (int pi = 0; pi < PPW; ++pi) op[pi] = mx[nt][pi];
        }
    }
}

extern "C" void kernel_launch(void* const* d_in, const int* in_sizes, int n_in,
                              void* d_out, int out_size, void* d_ws, size_t ws_size,
                              hipStream_t stream) {
    const float* x  = (const float*)d_in[0];
    const float* W1 = (const float*)d_in[1];
    const float* b1 = (const float*)d_in[2];
    const float* W2 = (const float*)d_in[3];
    const float* b2 = (const float*)d_in[4];
    float* out = (float*)d_out;

    const size_t MB = 1024 * 1024;
    const size_t KB = 1024;
    char* ws = (char*)d_ws;
    float*          xb   = (float*)(ws);                          // 0..8 MB
    unsigned short* xh   = (unsigned short*)(ws + 8 * MB);        // 8..12 MB
    float*          sq   = (float*)(ws + 12 * MB);                // 128 KB
    unsigned short* W1t  = (unsigned short*)(ws + 12 * MB + 256 * KB);  // 16 KB
    unsigned short* W2t  = (unsigned short*)(ws + 12 * MB + 272 * KB);  // 8 KB
    u32*            tau  = (u32*)(ws + 12 * MB + 320 * KB);       // 128 KB
    int*            cnt  = (int*)(ws + 12 * MB + 448 * KB);       // 128 KB
    int*            idxb = (int*)(ws + 13 * MB);                  // 2 MB
    u32*            cand16 = (u32*)(ws + 15 * MB);                // 32 MiB
    u32*            surv = (u32*)(ws + 47 * MB);                  // 24 MiB

    hipLaunchKernelGGL(k_transpose, dim3(NPB / 64, BB), dim3(64, 8), 0, stream, x, xb, xh, sq);
    hipLaunchKernelGGL(k_prepw, dim3(48), dim3(256), 0, stream, W1, W2, W1t, W2t);
    hipLaunchKernelGGL(k_gemm1, dim3(16, 64 * BB), dim3(256), 0, stream, xh, sq, cand16);
    hipLaunchKernelGGL(k_tau, dim3(NPTS / 4), dim3(256), 0, stream, cand16, tau);
    hipMemsetAsync(cnt, 0, (size_t)NPTS * 4, stream);
    hipLaunchKernelGGL(k_gemm2, dim3(NPB / 64, 64 * BB), dim3(256), 0, stream,
                       xh, sq, tau, cnt, surv);
    hipLaunchKernelGGL(k_sel, dim3(NPTS / 4), dim3(256), 0, stream,
                       surv, cnt, xb, sq, idxb);
    hipLaunchKernelGGL(k_mlp2, dim3(NPTS / PPW / 4), dim3(256), 0, stream,
                       xh, idxb, W1t, W2t, b1, b2, out);
}

// Round 27
// 393.869 us; speedup vs baseline: 1.5514x; 1.5514x over previous
//
#include <hip/hip_runtime.h>
#include <stdint.h>

#define BB 8
#define CCH 64
#define NPB 4096
#define NPTS (BB*NPB)   // 32768
#define PPW 8           // points per wave in k_mlp2
#define SCAP 192        // survivor cap per row

typedef float  f32x2  __attribute__((ext_vector_type(2)));
typedef float  f32x4v __attribute__((ext_vector_type(4)));
typedef short  bf16x8 __attribute__((ext_vector_type(8)));
typedef unsigned short u16x8 __attribute__((ext_vector_type(8)));
typedef unsigned long long u64;
typedef unsigned int u32;

// round-to-nearest-even f32 -> bf16 bits
__device__ __forceinline__ unsigned short f2bf(float x) {
    u32 u = __float_as_uint(x);
    u += 0x7FFFu + ((u >> 16) & 1u);
    return (unsigned short)(u >> 16);
}

// bitonic sort16 ascending (static indices, branchless) — proven since R6
template<typename T>
__device__ __forceinline__ void sort16(T* key) {
#pragma unroll
    for (int kk = 2; kk <= 16; kk <<= 1) {
#pragma unroll
        for (int j = kk >> 1; j > 0; j >>= 1) {
#pragma unroll
            for (int i = 0; i < 16; ++i) {
                int l = i ^ j;
                if (l > i) {
                    bool up = ((i & kk) == 0);
                    T a = key[i], c = key[l];
                    bool cond = up ? (c < a) : (a < c);
                    key[i] = cond ? c : a;
                    key[l] = cond ? a : c;
                }
            }
        }
    }
}

// keep 16 smallest of (list asc, key asc) -> list asc — proven since R6
template<typename T>
__device__ __forceinline__ void merge16(T* list, const T* key) {
    T m[16];
#pragma unroll
    for (int i = 0; i < 16; ++i) {
        T a = list[i], c = key[15 - i];
        m[i] = (c < a) ? c : a;
    }
#pragma unroll
    for (int j = 8; j > 0; j >>= 1) {
#pragma unroll
        for (int i = 0; i < 16; ++i) {
            if ((i & j) == 0) {
                T a = m[i], c = m[i + j];
                bool cond = c < a;
                m[i]     = cond ? c : a;
                m[i + j] = cond ? a : c;
            }
        }
    }
#pragma unroll
    for (int i = 0; i < 16; ++i) list[i] = m[i];
}

// ---------------- K1: fused transpose + sq + bf16 cast (PASSING since R19) ----------------
__global__ void k_transpose(const float* __restrict__ x, float* __restrict__ xb,
                            unsigned short* __restrict__ xh, float* __restrict__ sq) {
    __shared__ float tile[64][65];
    int b  = blockIdx.y;
    int n0 = blockIdx.x * 64;
    int tx = threadIdx.x, ty = threadIdx.y;   // 64 x 8
    const float* xp = x + (size_t)b * CCH * NPB;
#pragma unroll
    for (int r = 0; r < 8; ++r) {
        int c = ty + r * 8;
        tile[c][tx] = xp[(size_t)c * NPB + n0 + tx];
    }
    __syncthreads();
    float* xbp = xb + ((size_t)b * NPB + n0) * CCH;
    unsigned short* xhp = xh + ((size_t)b * NPB + n0) * CCH;
    float* sqp = sq + (size_t)b * NPB + n0;
#pragma unroll
    for (int r = 0; r < 8; ++r) {
        int nn = ty + r * 8;
        float v = tile[tx][nn];
        xbp[(size_t)nn * CCH + tx] = v;
        xhp[(size_t)nn * CCH + tx] = f2bf(v);
        float s = v * v;
#pragma unroll
        for (int o = 32; o > 0; o >>= 1) s += __shfl_xor(s, o);
        if (tx == 0) sqp[nn] = s;
    }
}

// ---------------- K1d: fold + transpose weights to bf16 (PASSING) ----------------
__global__ void k_prepw(const float* __restrict__ W1, const float* __restrict__ W2,
                        unsigned short* __restrict__ W1t, unsigned short* __restrict__ W2t) {
    int t = blockIdx.x * 256 + threadIdx.x;     // 12288 threads
    if (t < 8192) {
        int o = t >> 7, k = t & 127;
        float v = (k < 64) ? (W1[k * 64 + o] - W1[(64 + k) * 64 + o]) : W1[k * 64 + o];
        W1t[o * 128 + k] = f2bf(v);
    } else if (t < 12288) {
        int u = t - 8192;
        int o = u >> 6, j = u & 63;
        W2t[o * 64 + j] = f2bf(W2[j * 64 + o]);
    }
}

// ---------------- K2a: SAMPLED MFMA tile + per-row block top-16 (R26 body, PASSING) ----------------
__global__ __launch_bounds__(256) void k_gemm1(const unsigned short* __restrict__ xh,
                                               const float* __restrict__ sq,
                                               u32* __restrict__ cand16) {
    __shared__ float dtile[64][65];
    __shared__ u32 llist[64][65];
    int b = blockIdx.y >> 6;                    // scalar batch
    const unsigned short* xhB = xh + (size_t)b * NPB * CCH;
    const float* sqB = sq + (size_t)b * NPB;
    u32* candB = cand16 + (size_t)b * 16 * NPB * 16;
    int l = threadIdx.x & 63;
    int w = threadIdx.x >> 6;
    int m0 = (blockIdx.y & 63) * 64;
    int n0 = blockIdx.x * 256;                  // every 4th 64-col block
    const unsigned short* ap = xhB + (size_t)(m0 + w * 16 + (l & 15)) * CCH + ((l >> 4) * 8);
    bf16x8 a0 = *(const bf16x8*)ap;
    bf16x8 a1 = *(const bf16x8*)(ap + 32);
    f32x4v z = {0.f, 0.f, 0.f, 0.f};
    f32x4v acc[4];
#pragma unroll
    for (int cg = 0; cg < 4; ++cg) {
        const unsigned short* bp = xhB + (size_t)(n0 + cg * 16 + (l & 15)) * CCH + ((l >> 4) * 8);
        bf16x8 b0 = *(const bf16x8*)bp;
        bf16x8 b1 = *(const bf16x8*)(bp + 32);
        acc[cg] = __builtin_amdgcn_mfma_f32_16x16x32_bf16(a0, b0, z, 0, 0, 0);
        acc[cg] = __builtin_amdgcn_mfma_f32_16x16x32_bf16(a1, b1, acc[cg], 0, 0, 0);
    }
    int rb = m0 + w * 16 + (l >> 4) * 4;
    float4 sr = *(const float4*)(sqB + rb);
    float sqr[4] = {sr.x, sr.y, sr.z, sr.w};
#pragma unroll
    for (int cg = 0; cg < 4; ++cg) {
        int cit = cg * 16 + (l & 15);
        float sc = sqB[n0 + cit];
#pragma unroll
        for (int j = 0; j < 4; ++j) {
            float v = fmaxf(fmaf(-2.f, acc[cg][j], sqr[j] + sc), 0.f);
            dtile[w * 16 + (l >> 4) * 4 + j][cit] = v;
        }
    }
    __syncthreads();
    {
        int row = l, ch = w;
        u32 key[16];
#pragma unroll
        for (int e = 0; e < 16; ++e) {
            float v = dtile[row][ch * 16 + e];
            key[e] = ((u32)f2bf(v) << 16) | (u32)(n0 + ch * 16 + e);
        }
        sort16(key);
#pragma unroll
        for (int i = 0; i < 16; ++i) llist[row][ch * 16 + i] = key[i];
    }
    __syncthreads();
    if (threadIdx.x < 128) {
        int r2 = threadIdx.x & 63;
        int hf = threadIdx.x >> 6;
        u32 a[16], c[16];
#pragma unroll
        for (int i = 0; i < 16; ++i) a[i] = llist[r2][hf * 32 + i];
#pragma unroll
        for (int i = 0; i < 16; ++i) c[i] = llist[r2][hf * 32 + 16 + i];
        merge16(a, c);
#pragma unroll
        for (int i = 0; i < 16; ++i) llist[r2][hf * 32 + i] = a[i];
    }
    __syncthreads();
    if (threadIdx.x < 64) {
        int r2 = threadIdx.x;
        u32 list[16], tmp[16];
#pragma unroll
        for (int i = 0; i < 16; ++i) list[i] = llist[r2][i];
#pragma unroll
        for (int i = 0; i < 16; ++i) tmp[i] = llist[r2][32 + i];
        merge16(list, tmp);
        u32* cp = candB + ((size_t)blockIdx.x * NPB + (m0 + r2)) * 16;
#pragma unroll
        for (int i = 0; i < 16; ++i) cp[i] = list[i];
    }
}

// ---------------- K2b: per-row tau = 16th-smallest sampled bf16 value (R26, PASSING) ----------------
__global__ __launch_bounds__(256, 1) void k_tau(const u32* __restrict__ cand16,
                                                u32* __restrict__ tau) {
    int l  = threadIdx.x & 63;
    int rl = __builtin_amdgcn_readfirstlane(threadIdx.x >> 6);
    int rowg = blockIdx.x * 4 + rl;
    int b    = rowg >> 12;
    int row  = rowg & 4095;
    const u32* candB = cand16 + (size_t)b * 16 * NPB * 16;
    u32 karr[16];
    if (l < 16) {
        const uint4* cp = (const uint4*)(candB + ((size_t)l * NPB + row) * 16);
#pragma unroll
        for (int i = 0; i < 4; ++i) {
            uint4 v = cp[i];
            karr[4*i] = v.x; karr[4*i+1] = v.y; karr[4*i+2] = v.z; karr[4*i+3] = v.w;
        }
    } else {
#pragma unroll
        for (int i = 0; i < 16; ++i) karr[i] = 0xFFFFFFFFu;
    }
    u32 lo = 0, hi = 0x7FFFu;
#pragma unroll
    for (int it = 0; it < 15; ++it) {
        u32 mid = (lo + hi) >> 1;
        int c = 0;
#pragma unroll
        for (int i = 0; i < 16; ++i) c += ((karr[i] >> 16) <= mid) ? 1 : 0;
#pragma unroll
        for (int o = 32; o > 0; o >>= 1) c += __shfl_xor(c, o);
        bool ge = (c >= 16);
        lo = ge ? lo : (mid + 1);
        hi = ge ? mid : hi;
    }
    if (l == 0) tau[rowg] = hi;
}

// ---------------- K2c: full MFMA pass, threshold compare -> per-(row,tile) bitmask ----------------
// MFMA + epilogue math byte-identical to R26 k_gemm2 (PASSING numerics).
// NEW: survivors recorded via __ballot -> u64 tile mask, ONE plain store per
// (row, tile) by the group leader. Block (bx,by) uniquely owns (row,bx) ->
// NO ATOMICS (R26's 2M device atomics were the 384us: VALUBusy 12%).
__global__ __launch_bounds__(256) void k_gemm2(const unsigned short* __restrict__ xh,
                                               const float* __restrict__ sq,
                                               const u32* __restrict__ tau,
                                               u64* __restrict__ bm) {
    int b = blockIdx.y >> 6;                    // scalar batch
    const unsigned short* xhB = xh + (size_t)b * NPB * CCH;
    const float* sqB = sq + (size_t)b * NPB;
    int l = threadIdx.x & 63;
    int w = threadIdx.x >> 6;
    int m0 = (blockIdx.y & 63) * 64;
    int n0 = blockIdx.x * 64;
    const unsigned short* ap = xhB + (size_t)(m0 + w * 16 + (l & 15)) * CCH + ((l >> 4) * 8);
    bf16x8 a0 = *(const bf16x8*)ap;
    bf16x8 a1 = *(const bf16x8*)(ap + 32);
    f32x4v z = {0.f, 0.f, 0.f, 0.f};
    f32x4v acc[4];
#pragma unroll
    for (int cg = 0; cg < 4; ++cg) {
        const unsigned short* bp = xhB + (size_t)(n0 + cg * 16 + (l & 15)) * CCH + ((l >> 4) * 8);
        bf16x8 b0 = *(const bf16x8*)bp;
        bf16x8 b1 = *(const bf16x8*)(bp + 32);
        acc[cg] = __builtin_amdgcn_mfma_f32_16x16x32_bf16(a0, b0, z, 0, 0, 0);
        acc[cg] = __builtin_amdgcn_mfma_f32_16x16x32_bf16(a1, b1, acc[cg], 0, 0, 0);
    }
    int rb = m0 + w * 16 + (l >> 4) * 4;
    float4 sr = *(const float4*)(sqB + rb);
    float sqr[4] = {sr.x, sr.y, sr.z, sr.w};
    u32 tv[4];
#pragma unroll
    for (int j = 0; j < 4; ++j) tv[j] = tau[(b << 12) + rb + j];
    u64 rowmask[4] = {0ull, 0ull, 0ull, 0ull};
#pragma unroll
    for (int cg = 0; cg < 4; ++cg) {
        int cit = cg * 16 + (l & 15);
        float sc = sqB[n0 + cit];
#pragma unroll
        for (int j = 0; j < 4; ++j) {
            float v = fmaxf(fmaf(-2.f, acc[cg][j], sqr[j] + sc), 0.f);
            bool sv = ((u32)f2bf(v) <= tv[j]);
            u64 bal = __ballot(sv);
            // group g = l>>4 owns row rb+j; its cols live at ballot bits [g*16, g*16+16)
            u32 slice = (u32)((bal >> ((l >> 4) * 16)) & 0xFFFFu);
            rowmask[j] |= ((u64)slice) << (cg * 16);
        }
    }
    if ((l & 15) == 0) {
#pragma unroll
        for (int j = 0; j < 4; ++j) {
            int rg = (b << 12) + rb + j;
            bm[(size_t)rg * 64 + blockIdx.x] = rowmask[j];
        }
    }
}

// ---------------- K3: mask-scan + exact fp32 refine -> top-16 idx ----------------
// wave per row: lane l loads bm[row][l] (coalesced), popcount+prefix-scan ->
// scatter survivor cols into LDS slots (cap 192 = +8 sigma); then the R26
// 3-pass exact-refine + 64-lane bitonic sort VERBATIM (slots from LDS).
__global__ __launch_bounds__(256, 1) void k_sel(const u64* __restrict__ bm,
                                                const float* __restrict__ xb,
                                                const float* __restrict__ sq,
                                                int* __restrict__ idxo) {
    __shared__ u32 slots[4][SCAP];
    int l  = threadIdx.x & 63;
    int rl = __builtin_amdgcn_readfirstlane(threadIdx.x >> 6);
    int rowg = blockIdx.x * 4 + rl;             // scalar
    int b    = rowg >> 12;
    int row  = rowg & 4095;
    const float* xbB = xb + ((size_t)b << 12) * CCH;
    const float* sqB = sq + ((size_t)b << 12);
    const float* xr = xbB + (size_t)row * CCH;  // uniform -> s_load
    float rr[64];
#pragma unroll
    for (int i = 0; i < 16; ++i) {
        float4 v = *(const float4*)(xr + i * 4);
        rr[4*i] = v.x; rr[4*i+1] = v.y; rr[4*i+2] = v.z; rr[4*i+3] = v.w;
    }
    u64 mask = bm[(size_t)rowg * 64 + l];       // lane l = tile l
    int cl = __popcll(mask);
    int pre = cl;
#pragma unroll
    for (int d = 1; d < 64; d <<= 1) {
        int t = __shfl_up(pre, d);
        if (l >= d) pre += t;
    }
    int base = pre - cl;
    int ntot = __shfl(pre, 63);
    u32* sl = slots[rl];
    {   // scatter my survivors (avg ~1)
        u64 m2 = mask;
        int k = 0;
        while (m2) {
            int c = __builtin_ctzll(m2);
            m2 &= m2 - 1;
            int s = base + k;
            if (s < SCAP) sl[s] = (u32)(l * 64 + c);
            k++;
        }
    }
    int n = ntot > SCAP ? SCAP : ntot;
    u64 m = ~0ULL;
#pragma unroll
    for (int p = 0; p < 3; ++p) {
        if (p == 0 || n > p * 64) {
            int s = p * 64 + l;
            u64 key = ~0ULL;
            if (s < n) {
                int col = (int)sl[s];           // wave-local LDS, lgkmcnt-ordered
                const float* xj = xbB + (size_t)col * CCH;
                float lod = 0.f, hid = 0.f;
#pragma unroll
                for (int q = 0; q < 8; ++q) {
                    float4 v  = *(const float4*)(xj + q * 4);
                    float4 wv = *(const float4*)(xj + 32 + q * 4);
                    lod = fmaf(v.x,  rr[4*q+0], lod);
                    lod = fmaf(v.y,  rr[4*q+1], lod);
                    lod = fmaf(v.z,  rr[4*q+2], lod);
                    lod = fmaf(v.w,  rr[4*q+3], lod);
                    hid = fmaf(wv.x, rr[32+4*q+0], hid);
                    hid = fmaf(wv.y, rr[32+4*q+1], hid);
                    hid = fmaf(wv.z, rr[32+4*q+2], hid);
                    hid = fmaf(wv.w, rr[32+4*q+3], hid);
                }
                float d = fmaf(-2.f, lod + hid, sqB[col]);
                u32 fb = __float_as_uint(d);
                fb ^= (fb >> 31) ? 0xFFFFFFFFu : 0x80000000u;   // monotonic
                key = ((u64)fb << 32) | (u32)col;
            }
            // 64-lane bitonic sort ascending (R19-proven)
#pragma unroll
            for (int kk = 2; kk <= 64; kk <<= 1) {
#pragma unroll
                for (int j = kk >> 1; j > 0; j >>= 1) {
                    u64 pz = (u64)__shfl_xor((long long)key, j);
                    bool keep_min = (((l & kk) == 0) == ((l & j) == 0));
                    bool plt = pz < key;
                    key = keep_min ? (plt ? pz : key) : (plt ? key : pz);
                }
            }
            if (p == 0) {
                m = key;
            } else {
                u64 q = (u64)__shfl((long long)key, 63 - l);
                u64 mm = q < m ? q : m;
#pragma unroll
                for (int j = 32; j > 0; j >>= 1) {
                    u64 pz = (u64)__shfl_xor((long long)mm, j);
                    bool low = ((l & j) == 0);
                    bool plt = pz < mm;
                    mm = low ? (plt ? pz : mm) : (plt ? mm : pz);
                }
                m = mm;
            }
        }
    }
    if (l < 16) idxo[(size_t)rowg * 16 + l] = (int)(m & 0xFFFFFFFFu);
}

// ---------------- K4: MFMA edge-MLP + max over K (R18-R26 body, PASSING) ----------------
__global__ __launch_bounds__(256, 1) void k_mlp2(const unsigned short* __restrict__ xh,
                                                 const int* __restrict__ idx,
                                                 const unsigned short* __restrict__ W1t,
                                                 const unsigned short* __restrict__ W2t,
                                                 const float* __restrict__ b1,
                                                 const float* __restrict__ b2,
                                                 float* __restrict__ out) {
    __shared__ unsigned short h1l[4][16 * 72];
    int l   = threadIdx.x & 63;
    int wib = threadIdx.x >> 6;
    int e   = l & 15;
    int kg  = l >> 4;
    int wave = blockIdx.x * 4 + wib;            // 0..4095
    unsigned short* hl = h1l[wib];

    bf16x8 w1f[4][4];
#pragma unroll
    for (int nt = 0; nt < 4; ++nt)
#pragma unroll
        for (int s = 0; s < 4; ++s)
            w1f[nt][s] = *(const bf16x8*)(W1t + (size_t)(nt * 16 + e) * 128 + s * 32 + kg * 8);
    bf16x8 w2f[4][2];
#pragma unroll
    for (int nt = 0; nt < 4; ++nt)
#pragma unroll
        for (int s = 0; s < 2; ++s)
            w2f[nt][s] = *(const bf16x8*)(W2t + (size_t)(nt * 16 + e) * 64 + s * 32 + kg * 8);
    float b1v[4], b2v[4];
#pragma unroll
    for (int nt = 0; nt < 4; ++nt) { b1v[nt] = b1[nt * 16 + e]; b2v[nt] = b2[nt * 16 + e]; }

    int p0 = wave * PPW;
    int bb = p0 >> 12;
    int n0 = p0 & 4095;
    const unsigned short* xhB = xh + ((size_t)bb << 12) * CCH;
    f32x4v z = {0.f, 0.f, 0.f, 0.f};
    float mx[4][PPW];
#pragma unroll
    for (int nt = 0; nt < 4; ++nt)
#pragma unroll
        for (int pi = 0; pi < PPW; ++pi) mx[nt][pi] = 0.f;

#pragma unroll
    for (int pi = 0; pi < PPW; ++pi) {
        int n = n0 + pi;
        int je = idx[((size_t)(p0 + pi)) * 16 + e];
        bf16x8 a[4];
        a[0] = *(const bf16x8*)(xhB + (size_t)n * 64 + kg * 8);
        a[1] = *(const bf16x8*)(xhB + (size_t)n * 64 + 32 + kg * 8);
        a[2] = *(const bf16x8*)(xhB + (size_t)je * 64 + kg * 8);
        a[3] = *(const bf16x8*)(xhB + (size_t)je * 64 + 32 + kg * 8);
#pragma unroll
        for (int nt = 0; nt < 4; ++nt) {
            f32x4v acc = z;
#pragma unroll
            for (int s = 0; s < 4; ++s)
                acc = __builtin_amdgcn_mfma_f32_16x16x32_bf16(a[s], w1f[nt][s], acc, 0, 0, 0);
#pragma unroll
            for (int j = 0; j < 4; ++j) {
                float h = fmaxf(acc[j] + b1v[nt], 0.f);
                hl[(kg * 4 + j) * 72 + nt * 16 + e] = f2bf(h);
            }
        }
        bf16x8 a2[2];
        a2[0] = *(const bf16x8*)(hl + (size_t)e * 72 + kg * 8);
        a2[1] = *(const bf16x8*)(hl + (size_t)e * 72 + 32 + kg * 8);
#pragma unroll
        for (int nt = 0; nt < 4; ++nt) {
            f32x4v acc = z;
            acc = __builtin_amdgcn_mfma_f32_16x16x32_bf16(a2[0], w2f[nt][0], acc, 0, 0, 0);
            acc = __builtin_amdgcn_mfma_f32_16x16x32_bf16(a2[1], w2f[nt][1], acc, 0, 0, 0);
            float m4 = 0.f;
#pragma unroll
            for (int j = 0; j < 4; ++j)
                m4 = fmaxf(m4, fmaxf(acc[j] + b2v[nt], 0.f));
            mx[nt][pi] = m4;
        }
    }
#pragma unroll
    for (int nt = 0; nt < 4; ++nt)
#pragma unroll
        for (int pi = 0; pi < PPW; ++pi) {
            float v = mx[nt][pi];
            v = fmaxf(v, __shfl_xor(v, 16));
            v = fmaxf(v, __shfl_xor(v, 32));
            mx[nt][pi] = v;
        }
    if (kg == 0) {
#pragma unroll
        for (int nt = 0; nt < 4; ++nt) {
            float* op = out + ((size_t)bb * 64 + nt * 16 + e) * NPB + n0;
#pragma unroll
            for (int pi = 0; pi < PPW; ++pi) op[pi] = mx[nt][pi];
        }
    }
}

extern "C" void kernel_launch(void* const* d_in, const int* in_sizes, int n_in,
                              void* d_out, int out_size, void* d_ws, size_t ws_size,
                              hipStream_t stream) {
    const float* x  = (const float*)d_in[0];
    const float* W1 = (const float*)d_in[1];
    const float* b1 = (const float*)d_in[2];
    const float* W2 = (const float*)d_in[3];
    const float* b2 = (const float*)d_in[4];
    float* out = (float*)d_out;

    const size_t MB = 1024 * 1024;
    const size_t KB = 1024;
    char* ws = (char*)d_ws;
    float*          xb   = (float*)(ws);                          // 0..8 MB
    unsigned short* xh   = (unsigned short*)(ws + 8 * MB);        // 8..12 MB
    float*          sq   = (float*)(ws + 12 * MB);                // 128 KB
    unsigned short* W1t  = (unsigned short*)(ws + 12 * MB + 256 * KB);  // 16 KB
    unsigned short* W2t  = (unsigned short*)(ws + 12 * MB + 272 * KB);  // 8 KB
    u32*            tau  = (u32*)(ws + 12 * MB + 320 * KB);       // 128 KB
    int*            idxb = (int*)(ws + 13 * MB);                  // 2 MB
    u32*            cand16 = (u32*)(ws + 15 * MB);                // 32 MiB
    u64*            bm   = (u64*)(ws + 47 * MB);                  // 16 MiB

    hipLaunchKernelGGL(k_transpose, dim3(NPB / 64, BB), dim3(64, 8), 0, stream, x, xb, xh, sq);
    hipLaunchKernelGGL(k_prepw, dim3(48), dim3(256), 0, stream, W1, W2, W1t, W2t);
    hipLaunchKernelGGL(k_gemm1, dim3(16, 64 * BB), dim3(256), 0, stream, xh, sq, cand16);
    hipLaunchKernelGGL(k_tau, dim3(NPTS / 4), dim3(256), 0, stream, cand16, tau);
    hipLaunchKernelGGL(k_gemm2, dim3(NPB / 64, 64 * BB), dim3(256), 0, stream,
                       xh, sq, tau, bm);
    hipLaunchKernelGGL(k_sel, dim3(NPTS / 4), dim3(256), 0, stream,
                       bm, xb, sq, idxb);
    hipLaunchKernelGGL(k_mlp2, dim3(NPTS / PPW / 4), dim3(256), 0, stream,
                       xh, idxb, W1t, W2t, b1, b2, out);
}

// Round 28
// 320.694 us; speedup vs baseline: 1.9054x; 1.2282x over previous
//
#include <hip/hip_runtime.h>
#include <stdint.h>

#define BB 8
#define CCH 64
#define NPB 4096
#define NPTS (BB*NPB)   // 32768
#define PPW 8           // points per wave in k_mlp2

typedef float  f32x2  __attribute__((ext_vector_type(2)));
typedef float  f32x4v __attribute__((ext_vector_type(4)));
typedef short  bf16x8 __attribute__((ext_vector_type(8)));
typedef unsigned short u16x8 __attribute__((ext_vector_type(8)));
typedef unsigned long long u64;
typedef unsigned int u32;

// round-to-nearest-even f32 -> bf16 bits
__device__ __forceinline__ unsigned short f2bf(float x) {
    u32 u = __float_as_uint(x);
    u += 0x7FFFu + ((u >> 16) & 1u);
    return (unsigned short)(u >> 16);
}

// bitonic sort16 ascending (static indices, branchless) — proven since R6
template<typename T>
__device__ __forceinline__ void sort16(T* key) {
#pragma unroll
    for (int kk = 2; kk <= 16; kk <<= 1) {
#pragma unroll
        for (int j = kk >> 1; j > 0; j >>= 1) {
#pragma unroll
            for (int i = 0; i < 16; ++i) {
                int l = i ^ j;
                if (l > i) {
                    bool up = ((i & kk) == 0);
                    T a = key[i], c = key[l];
                    bool cond = up ? (c < a) : (a < c);
                    key[i] = cond ? c : a;
                    key[l] = cond ? a : c;
                }
            }
        }
    }
}

// keep 16 smallest of (list asc, key asc) -> list asc — proven since R6
template<typename T>
__device__ __forceinline__ void merge16(T* list, const T* key) {
    T m[16];
#pragma unroll
    for (int i = 0; i < 16; ++i) {
        T a = list[i], c = key[15 - i];
        m[i] = (c < a) ? c : a;
    }
#pragma unroll
    for (int j = 8; j > 0; j >>= 1) {
#pragma unroll
        for (int i = 0; i < 16; ++i) {
            if ((i & j) == 0) {
                T a = m[i], c = m[i + j];
                bool cond = c < a;
                m[i]     = cond ? c : a;
                m[i + j] = cond ? a : c;
            }
        }
    }
#pragma unroll
    for (int i = 0; i < 16; ++i) list[i] = m[i];
}

// ---------------- K1: fused transpose + sq + bf16 cast (R19 body, PASSING) ----------------
__global__ void k_transpose(const float* __restrict__ x, float* __restrict__ xb,
                            unsigned short* __restrict__ xh, float* __restrict__ sq) {
    __shared__ float tile[64][65];
    int b  = blockIdx.y;
    int n0 = blockIdx.x * 64;
    int tx = threadIdx.x, ty = threadIdx.y;   // 64 x 8
    const float* xp = x + (size_t)b * CCH * NPB;
#pragma unroll
    for (int r = 0; r < 8; ++r) {
        int c = ty + r * 8;
        tile[c][tx] = xp[(size_t)c * NPB + n0 + tx];
    }
    __syncthreads();
    float* xbp = xb + ((size_t)b * NPB + n0) * CCH;
    unsigned short* xhp = xh + ((size_t)b * NPB + n0) * CCH;
    float* sqp = sq + (size_t)b * NPB + n0;
#pragma unroll
    for (int r = 0; r < 8; ++r) {
        int nn = ty + r * 8;
        float v = tile[tx][nn];
        xbp[(size_t)nn * CCH + tx] = v;
        xhp[(size_t)nn * CCH + tx] = f2bf(v);
        float s = v * v;
#pragma unroll
        for (int o = 32; o > 0; o >>= 1) s += __shfl_xor(s, o);
        if (tx == 0) sqp[nn] = s;
    }
}

// ---------------- K1d: fold + transpose weights to bf16 (PASSING) ----------------
__global__ void k_prepw(const float* __restrict__ W1, const float* __restrict__ W2,
                        unsigned short* __restrict__ W1t, unsigned short* __restrict__ W2t) {
    int t = blockIdx.x * 256 + threadIdx.x;     // 12288 threads
    if (t < 8192) {
        int o = t >> 7, k = t & 127;
        float v = (k < 64) ? (W1[k * 64 + o] - W1[(64 + k) * 64 + o]) : W1[k * 64 + o];
        W1t[o * 128 + k] = f2bf(v);
    } else if (t < 12288) {
        int u = t - 8192;
        int o = u >> 6, j = u & 63;
        W2t[o * 64 + j] = f2bf(W2[j * 64 + o]);
    }
}

// ---------------- K2: MFMA 64x64 distance tile + fused per-row block top-16 ----------------
// R23/R25 body (best measured: 191 us, reproduced 3x). The one-pass gather
// cost (~176 us, measured via R27's selection-free k_gemm2) is the floor;
// fusing selection here amortizes it once.
__global__ __launch_bounds__(256) void k_gemm(const unsigned short* __restrict__ xh,
                                              const float* __restrict__ sq,
                                              u32* __restrict__ cand) {
    __shared__ float dtile[64][65];
    __shared__ u32 llist[64][65];
    int b = blockIdx.y >> 6;                    // scalar batch
    const unsigned short* xhB = xh + (size_t)b * NPB * CCH;
    const float* sqB = sq + (size_t)b * NPB;
    u32* candB = cand + (size_t)b * 64 * NPB * 16;
    int l = threadIdx.x & 63;
    int w = threadIdx.x >> 6;
    int m0 = (blockIdx.y & 63) * 64;
    int n0 = blockIdx.x * 64;
    const unsigned short* ap = xhB + (size_t)(m0 + w * 16 + (l & 15)) * CCH + ((l >> 4) * 8);
    bf16x8 a0 = *(const bf16x8*)ap;
    bf16x8 a1 = *(const bf16x8*)(ap + 32);
    f32x4v z = {0.f, 0.f, 0.f, 0.f};
    f32x4v acc[4];
#pragma unroll
    for (int cg = 0; cg < 4; ++cg) {
        const unsigned short* bp = xhB + (size_t)(n0 + cg * 16 + (l & 15)) * CCH + ((l >> 4) * 8);
        bf16x8 b0 = *(const bf16x8*)bp;
        bf16x8 b1 = *(const bf16x8*)(bp + 32);
        acc[cg] = __builtin_amdgcn_mfma_f32_16x16x32_bf16(a0, b0, z, 0, 0, 0);
        acc[cg] = __builtin_amdgcn_mfma_f32_16x16x32_bf16(a1, b1, acc[cg], 0, 0, 0);
    }
    int rb = m0 + w * 16 + (l >> 4) * 4;
    float4 sr = *(const float4*)(sqB + rb);
    float sqr[4] = {sr.x, sr.y, sr.z, sr.w};
#pragma unroll
    for (int cg = 0; cg < 4; ++cg) {
        int cit = cg * 16 + (l & 15);
        float sc = sqB[n0 + cit];
#pragma unroll
        for (int j = 0; j < 4; ++j) {
            float v = fmaxf(fmaf(-2.f, acc[cg][j], sqr[j] + sc), 0.f);
            dtile[w * 16 + (l >> 4) * 4 + j][cit] = v;
        }
    }
    __syncthreads();
    // phase 2: wave w sorts chunk w for all 64 rows (lane = row)
    {
        int row = l, ch = w;
        u32 key[16];
#pragma unroll
        for (int e = 0; e < 16; ++e) {
            float v = dtile[row][ch * 16 + e];
            key[e] = ((u32)f2bf(v) << 16) | (u32)(n0 + ch * 16 + e);
        }
        sort16(key);
#pragma unroll
        for (int i = 0; i < 16; ++i) llist[row][ch * 16 + i] = key[i];
    }
    __syncthreads();
    // phase 3a: 128 threads (2 per row): merge chunks (0,1) and (2,3)
    if (threadIdx.x < 128) {
        int r2 = threadIdx.x & 63;
        int hf = threadIdx.x >> 6;
        u32 a[16], c[16];
#pragma unroll
        for (int i = 0; i < 16; ++i) a[i] = llist[r2][hf * 32 + i];
#pragma unroll
        for (int i = 0; i < 16; ++i) c[i] = llist[r2][hf * 32 + 16 + i];
        merge16(a, c);
#pragma unroll
        for (int i = 0; i < 16; ++i) llist[r2][hf * 32 + i] = a[i];
    }
    __syncthreads();
    // phase 3b: 64 threads: final merge -> cand
    if (threadIdx.x < 64) {
        int r2 = threadIdx.x;
        u32 list[16], tmp[16];
#pragma unroll
        for (int i = 0; i < 16; ++i) list[i] = llist[r2][i];
#pragma unroll
        for (int i = 0; i < 16; ++i) tmp[i] = llist[r2][32 + i];
        merge16(list, tmp);
        u32* cp = candB + ((size_t)blockIdx.x * NPB + (m0 + r2)) * 16;
#pragma unroll
        for (int i = 0; i < 16; ++i) cp[i] = list[i];
    }
}

// ---------------- K3: threshold-select + exact fp32 refine -> idx ----------------
// R19/R25 body; binary search 15 iters over [0, 0x7FFF] (stored bf16 values
// are finite nonneg <= 0x7F80, so the converged v* is identical).
__global__ __launch_bounds__(256, 1) void k_post(const u32* __restrict__ cand,
                                                 const float* __restrict__ xb,
                                                 const float* __restrict__ sq,
                                                 int* __restrict__ idxo) {
    __shared__ u32 slots[4][64];
    int l  = threadIdx.x & 63;
    int rl = __builtin_amdgcn_readfirstlane(threadIdx.x >> 6);
    int rowg = blockIdx.x * 4 + rl;             // scalar global row
    int b    = rowg >> 12;                      // scalar batch
    int row  = rowg & 4095;
    const float* xbB = xb + ((size_t)b << 12) * CCH;
    const float* sqB = sq + ((size_t)b << 12);
    const u32* candB = cand + (size_t)b * 64 * NPB * 16;
    const float* xr = xbB + (size_t)row * CCH;  // uniform -> s_load
    float rr[64];
#pragma unroll
    for (int i = 0; i < 16; ++i) {
        float4 v = *(const float4*)(xr + i * 4);
        rr[4*i] = v.x; rr[4*i+1] = v.y; rr[4*i+2] = v.z; rr[4*i+3] = v.w;
    }
    u32 karr[16];
    {
        const uint4* cp = (const uint4*)(candB + ((size_t)l * NPB + row) * 16);
#pragma unroll
        for (int i = 0; i < 4; ++i) {
            uint4 v = cp[i];
            karr[4*i] = v.x; karr[4*i+1] = v.y; karr[4*i+2] = v.z; karr[4*i+3] = v.w;
        }
    }
    // ---- binary search on bf16 value for v* (count >= 48), 15 iters ----
    u32 lo = 0, hi = 0x7FFFu;
#pragma unroll
    for (int it = 0; it < 15; ++it) {
        u32 mid = (lo + hi) >> 1;
        int c = 0;
#pragma unroll
        for (int i = 0; i < 16; ++i) c += ((karr[i] >> 16) <= mid) ? 1 : 0;
#pragma unroll
        for (int o = 32; o > 0; o >>= 1) c += __shfl_xor(c, o);
        bool ge = (c >= 48);
        lo = ge ? lo : (mid + 1);
        hi = ge ? mid : hi;
    }
    u32 vstar = hi;
    // ---- scatter survivors (val <= v*) into <=64 LDS slots ----
    int cnt = 0;
#pragma unroll
    for (int i = 0; i < 16; ++i) cnt += ((karr[i] >> 16) <= vstar) ? 1 : 0;
    int pre = cnt;
#pragma unroll
    for (int d = 1; d < 64; d <<= 1) {
        int t = __shfl_up(pre, d);
        if (l >= d) pre += t;
    }
    int base = pre - cnt;
    u32* sl = slots[rl];                        // wave-private row
    sl[l] = 0xFFFFFFFFu;                        // in-wave DS order: init first
#pragma unroll
    for (int i = 0; i < 16; ++i) {
        if (i < cnt) {
            int s = base + i;
            if (s < 64) sl[s] = karr[i];
        }
    }
    u32 mk = sl[l];                             // wave-local, lgkmcnt-ordered
    // ---- exact fp32 distance for my survivor (byte-identical math) ----
    u64 key = ~0ULL;
    if (mk != 0xFFFFFFFFu) {
        int col = (int)(mk & 0xFFFFu);
        const float* xj = xbB + (size_t)col * CCH;
        float lod = 0.f, hid = 0.f;
#pragma unroll
        for (int q = 0; q < 8; ++q) {
            float4 v  = *(const float4*)(xj + q * 4);
            float4 wv = *(const float4*)(xj + 32 + q * 4);
            lod = fmaf(v.x,  rr[4*q+0], lod);
            lod = fmaf(v.y,  rr[4*q+1], lod);
            lod = fmaf(v.z,  rr[4*q+2], lod);
            lod = fmaf(v.w,  rr[4*q+3], lod);
            hid = fmaf(wv.x, rr[32+4*q+0], hid);
            hid = fmaf(wv.y, rr[32+4*q+1], hid);
            hid = fmaf(wv.z, rr[32+4*q+2], hid);
            hid = fmaf(wv.w, rr[32+4*q+3], hid);
        }
        float d = fmaf(-2.f, lod + hid, sqB[col]);
        u32 fb = __float_as_uint(d);
        fb ^= (fb >> 31) ? 0xFFFFFFFFu : 0x80000000u;   // monotonic
        key = ((u64)fb << 32) | (u32)col;
    }
    // ---- 64-lane bitonic sort ascending on u64 keys ----
#pragma unroll
    for (int kk = 2; kk <= 64; kk <<= 1) {
#pragma unroll
        for (int j = kk >> 1; j > 0; j >>= 1) {
            u64 p = (u64)__shfl_xor((long long)key, j);
            bool keep_min = (((l & kk) == 0) == ((l & j) == 0));
            bool plt = p < key;
            key = keep_min ? (plt ? p : key) : (plt ? key : p);
        }
    }
    if (l < 16) idxo[(size_t)rowg * 16 + l] = (int)(key & 0xFFFFFFFFu);
}

// ---------------- K4: MFMA edge-MLP + max over K (R18-R25 body, PASSING) ----------------
__global__ __launch_bounds__(256, 1) void k_mlp2(const unsigned short* __restrict__ xh,
                                                 const int* __restrict__ idx,
                                                 const unsigned short* __restrict__ W1t,
                                                 const unsigned short* __restrict__ W2t,
                                                 const float* __restrict__ b1,
                                                 const float* __restrict__ b2,
                                                 float* __restrict__ out) {
    __shared__ unsigned short h1l[4][16 * 72];
    int l   = threadIdx.x & 63;
    int wib = threadIdx.x >> 6;
    int e   = l & 15;
    int kg  = l >> 4;
    int wave = blockIdx.x * 4 + wib;            // 0..4095
    unsigned short* hl = h1l[wib];

    bf16x8 w1f[4][4];
#pragma unroll
    for (int nt = 0; nt < 4; ++nt)
#pragma unroll
        for (int s = 0; s < 4; ++s)
            w1f[nt][s] = *(const bf16x8*)(W1t + (size_t)(nt * 16 + e) * 128 + s * 32 + kg * 8);
    bf16x8 w2f[4][2];
#pragma unroll
    for (int nt = 0; nt < 4; ++nt)
#pragma unroll
        for (int s = 0; s < 2; ++s)
            w2f[nt][s] = *(const bf16x8*)(W2t + (size_t)(nt * 16 + e) * 64 + s * 32 + kg * 8);
    float b1v[4], b2v[4];
#pragma unroll
    for (int nt = 0; nt < 4; ++nt) { b1v[nt] = b1[nt * 16 + e]; b2v[nt] = b2[nt * 16 + e]; }

    int p0 = wave * PPW;
    int bb = p0 >> 12;
    int n0 = p0 & 4095;
    const unsigned short* xhB = xh + ((size_t)bb << 12) * CCH;
    f32x4v z = {0.f, 0.f, 0.f, 0.f};
    float mx[4][PPW];
#pragma unroll
    for (int nt = 0; nt < 4; ++nt)
#pragma unroll
        for (int pi = 0; pi < PPW; ++pi) mx[nt][pi] = 0.f;

#pragma unroll
    for (int pi = 0; pi < PPW; ++pi) {
        int n = n0 + pi;
        int je = idx[((size_t)(p0 + pi)) * 16 + e];
        bf16x8 a[4];
        a[0] = *(const bf16x8*)(xhB + (size_t)n * 64 + kg * 8);
        a[1] = *(const bf16x8*)(xhB + (size_t)n * 64 + 32 + kg * 8);
        a[2] = *(const bf16x8*)(xhB + (size_t)je * 64 + kg * 8);
        a[3] = *(const bf16x8*)(xhB + (size_t)je * 64 + 32 + kg * 8);
#pragma unroll
        for (int nt = 0; nt < 4; ++nt) {
            f32x4v acc = z;
#pragma unroll
            for (int s = 0; s < 4; ++s)
                acc = __builtin_amdgcn_mfma_f32_16x16x32_bf16(a[s], w1f[nt][s], acc, 0, 0, 0);
#pragma unroll
            for (int j = 0; j < 4; ++j) {
                float h = fmaxf(acc[j] + b1v[nt], 0.f);
                hl[(kg * 4 + j) * 72 + nt * 16 + e] = f2bf(h);
            }
        }
        bf16x8 a2[2];
        a2[0] = *(const bf16x8*)(hl + (size_t)e * 72 + kg * 8);
        a2[1] = *(const bf16x8*)(hl + (size_t)e * 72 + 32 + kg * 8);
#pragma unroll
        for (int nt = 0; nt < 4; ++nt) {
            f32x4v acc = z;
            acc = __builtin_amdgcn_mfma_f32_16x16x32_bf16(a2[0], w2f[nt][0], acc, 0, 0, 0);
            acc = __builtin_amdgcn_mfma_f32_16x16x32_bf16(a2[1], w2f[nt][1], acc, 0, 0, 0);
            float m4 = 0.f;
#pragma unroll
            for (int j = 0; j < 4; ++j)
                m4 = fmaxf(m4, fmaxf(acc[j] + b2v[nt], 0.f));
            mx[nt][pi] = m4;
        }
    }
#pragma unroll
    for (int nt = 0; nt < 4; ++nt)
#pragma unroll
        for (int pi = 0; pi < PPW; ++pi) {
            float v = mx[nt][pi];
            v = fmaxf(v, __shfl_xor(v, 16));
            v = fmaxf(v, __shfl_xor(v, 32));
            mx[nt][pi] = v;
        }
    if (kg == 0) {
#pragma unroll
        for (int nt = 0; nt < 4; ++nt) {
            float* op = out + ((size_t)bb * 64 + nt * 16 + e) * NPB + n0;
#pragma unroll
            for (int pi = 0; pi < PPW; ++pi) op[pi] = mx[nt][pi];
        }
    }
}

extern "C" void kernel_launch(void* const* d_in, const int* in_sizes, int n_in,
                              void* d_out, int out_size, void* d_ws, size_t ws_size,
                              hipStream_t stream) {
    const float* x  = (const float*)d_in[0];
    const float* W1 = (const float*)d_in[1];
    const float* b1 = (const float*)d_in[2];
    const float* W2 = (const float*)d_in[3];
    const float* b2 = (const float*)d_in[4];
    float* out = (float*)d_out;

    const size_t MB = 1024 * 1024;
    char* ws = (char*)d_ws;
    float*          xb  = (float*)(ws);                         // 8 MB
    unsigned short* xh  = (unsigned short*)(ws + 8 * MB);       // 4 MB
    float*          sq  = (float*)(ws + 12 * MB);               // 128 KB
    unsigned short* W1t = (unsigned short*)(ws + 12 * MB + 256 * 1024);   // 16 KB
    unsigned short* W2t = (unsigned short*)(ws + 12 * MB + 272 * 1024);   // 8 KB
    u32*            cand = (u32*)(ws + 13 * MB);
    size_t candAll = (size_t)BB * 64 * NPB * 16 * 4;            // 128 MiB
    size_t needF = 13 * MB + candAll + (size_t)NPTS * 16 * 4;

    hipLaunchKernelGGL(k_transpose, dim3(NPB / 64, BB), dim3(64, 8), 0, stream, x, xb, xh, sq);
    hipLaunchKernelGGL(k_prepw, dim3(48), dim3(256), 0, stream, W1, W2, W1t, W2t);

    if (ws_size >= needF + MB) {
        int* idxb = (int*)(ws + 13 * MB + candAll);
        hipLaunchKernelGGL(k_gemm, dim3(NPB / 64, 64 * BB), dim3(256), 0, stream,
                           xh, sq, cand);
        hipLaunchKernelGGL(k_post, dim3(NPTS / 4), dim3(256), 0, stream,
                           cand, xb, sq, idxb);
        hipLaunchKernelGGL(k_mlp2, dim3(NPTS / PPW / 4), dim3(256), 0, stream,
                           xh, idxb, W1t, W2t, b1, b2, out);
    } else {
        // fallback: per-batch loop (b=0 inside kernels via grid y=64); cand = 16 MiB
        int* idxb = (int*)(ws + 30 * MB);
        for (int b = 0; b < BB; ++b) {
            const unsigned short* xhB = xh + (size_t)b * NPB * CCH;
            const float* xbB = xb + (size_t)b * NPB * CCH;
            const float* sqB = sq + (size_t)b * NPB;
            hipLaunchKernelGGL(k_gemm, dim3(NPB / 64, 64), dim3(256), 0, stream,
                               xhB, sqB, cand);
            hipLaunchKernelGGL(k_post, dim3(NPB / 4), dim3(256), 0, stream,
                               cand, xbB, sqB, idxb + (size_t)b * NPB * 16);
        }
        hipLaunchKernelGGL(k_mlp2, dim3(NPTS / PPW / 4), dim3(256), 0, stream,
                           xh, idxb, W1t, W2t, b1, b2, out);
    }
}